// Round 1
// 1085.986 us; speedup vs baseline: 1.0041x; 1.0041x over previous
//
#include <hip/hip_runtime.h>
#include <stdint.h>

typedef unsigned short u16;
typedef short s16x8 __attribute__((ext_vector_type(8)));
typedef float f32x4 __attribute__((ext_vector_type(4)));

__device__ __forceinline__ float bf2f(u16 u) {
  union { unsigned u; float f; } c; c.u = ((unsigned)u) << 16; return c.f;
}
__device__ __forceinline__ u16 f2bf(float f) {
  union { float f; unsigned u; } c; c.f = f;
  unsigned r = c.u + 0x7FFFu + ((c.u >> 16) & 1u);
  return (u16)(r >> 16);
}
__device__ __forceinline__ unsigned encf(float x) {
  union { float f; unsigned u; } c; c.f = x;
  return (c.u & 0x80000000u) ? ~c.u : (c.u | 0x80000000u);
}
__device__ __forceinline__ float decf(unsigned e) {
  union { unsigned u; float f; } c;
  c.u = (e & 0x80000000u) ? (e ^ 0x80000000u) : ~e;
  return c.f;
}
__device__ __forceinline__ f32x4 mfma16(s16x8 a, s16x8 b, f32x4 c) {
  return __builtin_amdgcn_mfma_f32_16x16x32_bf16(a, b, c, 0, 0, 0);
}
__device__ __forceinline__ float relu(float x) { return x > 0.f ? x : 0.f; }

// async global->LDS 16B copy (CK-style addrspace casts)
__device__ __forceinline__ void gload_lds16(const void* g, void* l) {
  auto* gp = reinterpret_cast<const __attribute__((address_space(1))) unsigned*>(
      reinterpret_cast<uintptr_t>(g));
  auto* lp = reinterpret_cast<__attribute__((address_space(3))) unsigned*>(
      reinterpret_cast<uintptr_t>(l));
  __builtin_amdgcn_global_load_lds(gp, lp, 16, 0, 0);
}

// ---- dtype-generic loaders: element index ei, F32 selects f32 vs bf16 buffers ----
template <int F32>
__device__ __forceinline__ void loadf8(const void* p, size_t ei, float* o) {
  if (F32) {
    const float* f = (const float*)p + ei;
    f32x4 a = *(const f32x4*)f;
    f32x4 b = *(const f32x4*)(f + 4);
#pragma unroll
    for (int j = 0; j < 4; ++j) { o[j] = a[j]; o[4 + j] = b[j]; }
  } else {
    s16x8 v = *(const s16x8*)((const u16*)p + ei);
#pragma unroll
    for (int j = 0; j < 8; ++j) o[j] = bf2f((u16)v[j]);
  }
}
template <int F32>
__device__ __forceinline__ s16x8 load8b(const void* p, size_t ei) {  // -> 8 bf16
  if (F32) {
    float o[8]; loadf8<1>(p, ei, o);
    s16x8 r;
#pragma unroll
    for (int j = 0; j < 8; ++j) r[j] = (short)f2bf(o[j]);
    return r;
  } else {
    return *(const s16x8*)((const u16*)p + ei);
  }
}
template <int F32>
__device__ __forceinline__ float ld1(const void* p, size_t ei) {
  return F32 ? ((const float*)p)[ei] : bf2f(((const u16*)p)[ei]);
}

// ---------------- detect dtype + init ws ----------------
// ws (u32): [0:64) egws, [64:192) rgws, [192:256) tpart, [256] flag (1 = f32)
__global__ void k_detect(const u16* __restrict__ entity, const u16* __restrict__ rel,
                         unsigned* __restrict__ ws) {
  __shared__ unsigned cnt[256];
  const int t = threadIdx.x;
  ws[t] = 0u;
  unsigned c = 0;
  for (int i = t; i < 16384; i += 256) {
    unsigned u = rel[i];
    if ((u & 0x7F80u) == 0x7F80u) ++c;  // exp all-ones: impossible in genuine bf16 data
  }
  for (int i = t; i < 8192; i += 256) {
    unsigned u = entity[i];
    if ((u & 0x7F80u) == 0x7F80u) ++c;
  }
  cnt[t] = c;
  __syncthreads();
  for (int st = 128; st > 0; st >>= 1) {
    if (t < st) cnt[t] += cnt[t + st];
    __syncthreads();
  }
  if (t == 0) ws[256] = cnt[0] ? 1u : 0u;
}

// ---------------- entity encoder: 2048 rows, 128->32->8->1, group max ----------------
template <int F32>
__global__ __launch_bounds__(256) void k_ent(
    const void* __restrict__ entity, const void* __restrict__ ew1, const void* __restrict__ eb1,
    const void* __restrict__ ew2, const void* __restrict__ eb2,
    const void* __restrict__ ew3, const void* __restrict__ eb3,
    unsigned* __restrict__ egws, const unsigned* __restrict__ flag) {
  if (*flag != (unsigned)F32) return;
  __shared__ __align__(16) u16 xl[32 * 136];
  __shared__ __align__(16) u16 w1l[32 * 136];
  __shared__ float h1l[32 * 33];
  __shared__ float h2l[32 * 9];
  const int t = threadIdx.x;
  const int row0 = blockIdx.x * 32;
#pragma unroll
  for (int p = 0; p < 2; ++p) {
    int lin = p * 256 + t, rr = lin >> 4, cc = lin & 15;
    *(s16x8*)(xl + rr * 136 + cc * 8) =
        load8b<F32>(entity, (size_t)(row0 + rr) * 128 + cc * 8);
    *(s16x8*)(w1l + rr * 136 + cc * 8) = load8b<F32>(ew1, (size_t)rr * 128 + cc * 8);
  }
  __syncthreads();
  {  // layer1
    const int r = t >> 3, g = t & 7;
    float acc[4] = {0.f, 0.f, 0.f, 0.f};
#pragma unroll 4
    for (int c = 0; c < 16; ++c) {
      s16x8 xv = *(const s16x8*)(xl + r * 136 + c * 8);
      float xf[8];
#pragma unroll
      for (int j = 0; j < 8; ++j) xf[j] = bf2f((u16)xv[j]);
#pragma unroll
      for (int s = 0; s < 4; ++s) {
        s16x8 wv = *(const s16x8*)(w1l + (g + 8 * s) * 136 + c * 8);
#pragma unroll
        for (int j = 0; j < 8; ++j) acc[s] += xf[j] * bf2f((u16)wv[j]);
      }
    }
#pragma unroll
    for (int s = 0; s < 4; ++s)
      h1l[r * 33 + g + 8 * s] = relu(acc[s] + ld1<F32>(eb1, g + 8 * s));
  }
  __syncthreads();
  {  // layer2
    const int r = t >> 3, o = t & 7;
    float a = ld1<F32>(eb2, o);
#pragma unroll 8
    for (int k = 0; k < 32; ++k) a += h1l[r * 33 + k] * ld1<F32>(ew2, o * 32 + k);
    h2l[r * 9 + o] = relu(a);
  }
  __syncthreads();
  if (t < 32) {  // layer3 + type + group max
    float s = ld1<F32>(eb3, 0);
#pragma unroll
    for (int k = 0; k < 8; ++k) s += h2l[t * 9 + k] * ld1<F32>(ew3, k);
    int ty = 0;
#pragma unroll
    for (int c = 0; c < 8; ++c) {
      s16x8 v = *(const s16x8*)(xl + t * 136 + c * 8);
#pragma unroll
      for (int j = 0; j < 8; ++j)
        if ((u16)v[j] == (u16)0x3F80) ty = c * 8 + j;
    }
    atomicMax(egws + ty, encf(s));
  }
}

// ---------------- target encoder layer1 partials ----------------
template <int F32>
__global__ __launch_bounds__(256) void k_tgt(const void* __restrict__ target,
                                             const void* __restrict__ tw1,
                                             float* __restrict__ tpart,
                                             const unsigned* __restrict__ flag) {
  if (*flag != (unsigned)F32) return;
  __shared__ float red[256];
  const int t = threadIdx.x;
  const int o = blockIdx.x >> 2, c = blockIdx.x & 3;
  float a = 0.f;
  for (int i = t; i < 2116; i += 256) {
    float xf[8], wf[8];
    loadf8<F32>(target, (size_t)c * 16928 + i * 8, xf);
    loadf8<F32>(tw1, (size_t)o * 67712 + c * 16928 + i * 8, wf);
#pragma unroll
    for (int j = 0; j < 8; ++j) a += xf[j] * wf[j];
  }
  red[t] = a;
  __syncthreads();
  for (int st = 128; st > 0; st >>= 1) {
    if (t < st) red[t] += red[t + st];
    __syncthreads();
  }
  if (t == 0) atomicAdd(tpart + o, red[0]);
}

// ---------------- relationship encoder (f32 fallback path, unchanged) ----------------
#define RK 2240
template <int F32>
__global__ __launch_bounds__(256) void k_rel(
    const void* __restrict__ rel, const void* __restrict__ rw1, const void* __restrict__ rb1,
    const void* __restrict__ rw2, const void* __restrict__ rb2,
    const void* __restrict__ rw3, const void* __restrict__ rb3,
    const void* __restrict__ rw4, const void* __restrict__ rb4,
    const void* __restrict__ rw5, const void* __restrict__ rb5,
    unsigned* __restrict__ rgws, const unsigned* __restrict__ flag) {
  if (*flag != (unsigned)F32) return;
  __shared__ __align__(16) unsigned char sm[53760];
  u16* smA = (u16*)sm;
  u16* smB = (u16*)(sm + 8192);
  u16* r0 = (u16*)sm;               // later h2 [128][72]
  u16* smRF = (u16*)(sm + 18432);   // rf1 [128][136]
  int* styp = (int*)(sm + 53248);

  const int t = threadIdx.x;
  const int lane = t & 63;
  const int wid = t >> 6;
  const int row0 = blockIdx.x * 128;
  const int fr = lane & 15, fq = lane >> 4;

  if (t < 128) {  // one-hot type scan, cols 0..127
    int ty = 0;
#pragma unroll 4
    for (int c = 0; c < 16; ++c) {
      s16x8 v = load8b<F32>(rel, (size_t)(row0 + t) * RK + c * 8);
#pragma unroll
      for (int j = 0; j < 8; ++j)
        if ((u16)v[j] == (u16)0x3F80) ty = c * 8 + j;
    }
    styp[t] = ty;
  }

  // ---- layer1: C[128][128] = rel_tile @ rw1^T, K=2240 ----
  const int wm = wid >> 1, wn = wid & 1;
  f32x4 acc[4][4];
#pragma unroll
  for (int i = 0; i < 4; ++i)
#pragma unroll
    for (int j = 0; j < 4; ++j) acc[i][j] = f32x4{0.f, 0.f, 0.f, 0.f};

  const size_t gA0 = (size_t)(row0 + (t >> 2)) * RK + (t & 3) * 8;
  const size_t gB0 = (size_t)(t >> 2) * RK + (t & 3) * 8;

  for (int ki = 0; ki < 70; ++ki) {
    const int k0 = ki * 32;
    s16x8 va0 = load8b<F32>(rel, gA0 + k0);
    s16x8 va1 = load8b<F32>(rel, gA0 + (size_t)64 * RK + k0);
    s16x8 vb0 = load8b<F32>(rw1, gB0 + k0);
    s16x8 vb1 = load8b<F32>(rw1, gB0 + (size_t)64 * RK + k0);
    __syncthreads();
    *(s16x8*)(smA + t * 8) = va0;
    *(s16x8*)(smA + 2048 + t * 8) = va1;
    *(s16x8*)(smB + t * 8) = vb0;
    *(s16x8*)(smB + 2048 + t * 8) = vb1;
    __syncthreads();
    s16x8 a[4], b[4];
#pragma unroll
    for (int i = 0; i < 4; ++i)
      a[i] = *(const s16x8*)(smA + (wm * 64 + i * 16 + fr) * 32 + fq * 8);
#pragma unroll
    for (int j = 0; j < 4; ++j)
      b[j] = *(const s16x8*)(smB + (wn * 64 + j * 16 + fr) * 32 + fq * 8);
#pragma unroll
    for (int i = 0; i < 4; ++i)
#pragma unroll
      for (int j = 0; j < 4; ++j) acc[i][j] = mfma16(a[i], b[j], acc[i][j]);
  }
  __syncthreads();

  // epilogue L1 -> smRF[128][136] bf16
#pragma unroll
  for (int j = 0; j < 4; ++j) {
    const int col = wn * 64 + j * 16 + fr;
    const float bias = ld1<F32>(rb1, col);
#pragma unroll
    for (int i = 0; i < 4; ++i) {
      const int rbase = wm * 64 + i * 16 + fq * 4;
#pragma unroll
      for (int r = 0; r < 4; ++r)
        smRF[(rbase + r) * 136 + col] = f2bf(relu(acc[i][j][r] + bias));
    }
  }
  __syncthreads();

  // ---- layers 2-5: VALU, thread t owns row t ----
  if (t < 128) {
    const u16* rfrow = smRF + t * 136;
    for (int o = 0; o < 64; ++o) {
      float a = ld1<F32>(rb2, o);
      for (int k = 0; k < 128; k += 8) {
        float wf[8];
        loadf8<F32>(rw2, o * 128 + k, wf);
#pragma unroll
        for (int j = 0; j < 8; ++j) a += bf2f(rfrow[k + j]) * wf[j];
      }
      r0[t * 72 + o] = f2bf(relu(a));
    }
    const u16* h2row = r0 + t * 72;
    float h3[32];
#pragma unroll
    for (int o = 0; o < 32; ++o) {
      float a = ld1<F32>(rb3, o);
      for (int k = 0; k < 64; k += 8) {
        float wf[8];
        loadf8<F32>(rw3, o * 64 + k, wf);
#pragma unroll
        for (int j = 0; j < 8; ++j) a += bf2f(h2row[k + j]) * wf[j];
      }
      h3[o] = relu(a);
    }
    float h4[8];
#pragma unroll
    for (int o = 0; o < 8; ++o) {
      float a = ld1<F32>(rb4, o);
#pragma unroll
      for (int k = 0; k < 32; ++k) a += h3[k] * ld1<F32>(rw4, o * 32 + k);
      h4[o] = relu(a);
    }
    float s = ld1<F32>(rb5, 0);
#pragma unroll
    for (int k = 0; k < 8; ++k) s += h4[k] * ld1<F32>(rw5, k);
    atomicMax(rgws + styp[t], encf(s));
  }
}

// ---------------- relationship encoder, bf16 fast path ----------------
// Layer1: 128x128 tile, BK=64, double-buffered global_load_lds(16B) with
// XOR-swizzled source (rule #21: linear DMA dest + pre-swizzled global src +
// swizzled ds_read). Layer2 via MFMA from LDS; layers 3-5 VALU, 2 thr/row.
__global__ __launch_bounds__(256, 2) void k_relb(
    const u16* __restrict__ rel, const u16* __restrict__ rw1, const u16* __restrict__ rb1,
    const u16* __restrict__ rw2, const u16* __restrict__ rb2,
    const u16* __restrict__ rw3, const u16* __restrict__ rb3,
    const u16* __restrict__ rw4, const u16* __restrict__ rb4,
    const u16* __restrict__ rw5, const u16* __restrict__ rb5,
    unsigned* __restrict__ rgws, const unsigned* __restrict__ flag) {
  if (*flag != 0u) return;
  // LDS map: main loop: bufA0[16K] bufB0[16K] bufA1[16K] bufB1[16K]
  // tail (aliased, after final barrier): smRF[128][136]b16 @0 (34816),
  // w2l[64][136]b16 @34816 (17408), h2[128][72]b16 @52224 (18432)
  __shared__ __align__(16) unsigned char sm[70656];
  const int t = threadIdx.x;
  const int lane = t & 63;
  const int wid = t >> 6;
  const int fr = lane & 15, fq = lane >> 4;
  const int wm = wid >> 1, wn = wid & 1;
  const int l8 = lane >> 3;               // row-within-8-row-block for DMA
  const int row0 = blockIdx.x * 128;
  const int swu = ((lane & 7) ^ l8) * 8;  // pre-swizzled global col (u16) within 64-chunk
  const int swa = (fr & 7) << 3;          // XOR (u16 units) for swizzled frag reads

  f32x4 acc[4][4];
#pragma unroll
  for (int i = 0; i < 4; ++i)
#pragma unroll
    for (int j = 0; j < 4; ++j) acc[i][j] = f32x4{0.f, 0.f, 0.f, 0.f};

  // prologue: stage K-tile 0 into buffer 0
  {
    unsigned char* ba = sm;
    unsigned char* bb = sm + 16384;
#pragma unroll
    for (int it = 0; it < 4; ++it) {
      const int rr = wid * 32 + it * 8;   // 8-row block base (wave-uniform)
      gload_lds16(rel + (size_t)(row0 + rr + l8) * RK + swu, ba + rr * 128);
      gload_lds16(rw1 + (size_t)(rr + l8) * RK + swu, bb + rr * 128);
    }
  }
  __syncthreads();

  int ty = 0;
#pragma unroll 1
  for (int ki = 0; ki < 35; ++ki) {
    if (ki < 34) {  // issue next-tile DMA before compute (2-phase pipeline)
      unsigned char* ba = sm + ((ki + 1) & 1) * 32768;
      unsigned char* bb = ba + 16384;
      const int k0 = (ki + 1) * 64;
#pragma unroll
      for (int it = 0; it < 4; ++it) {
        const int rr = wid * 32 + it * 8;
        gload_lds16(rel + (size_t)(row0 + rr + l8) * RK + k0 + swu, ba + rr * 128);
        gload_lds16(rw1 + (size_t)(rr + l8) * RK + k0 + swu, bb + rr * 128);
      }
    }
    const u16* ba = (const u16*)(sm + (ki & 1) * 32768);
    const u16* bb = ba + 8192;
#pragma unroll
    for (int ks = 0; ks < 2; ++ks) {
      s16x8 a[4], b[4];
#pragma unroll
      for (int i = 0; i < 4; ++i)
        a[i] = *(const s16x8*)(ba + (wm * 64 + i * 16 + fr) * 64 + ((ks * 32 + fq * 8) ^ swa));
#pragma unroll
      for (int j = 0; j < 4; ++j)
        b[j] = *(const s16x8*)(bb + (wn * 64 + j * 16 + fr) * 64 + ((ks * 32 + fq * 8) ^ swa));
#pragma unroll
      for (int i = 0; i < 4; ++i)
#pragma unroll
        for (int j = 0; j < 4; ++j) acc[i][j] = mfma16(a[i], b[j], acc[i][j]);
    }
    if (ki < 2) {  // one-hot type scan from staged A-tile (cols 0..127), 2 thr/row
      const int r = t >> 1, hs = t & 1;
      const int rsw = (r & 7) << 3;
#pragma unroll
      for (int c = 0; c < 4; ++c) {
        const int cc = hs * 4 + c;
        s16x8 v = *(const s16x8*)(ba + r * 64 + ((cc * 8) ^ rsw));
#pragma unroll
        for (int j = 0; j < 8; ++j)
          if ((u16)v[j] == (u16)0x3F80) ty = ki * 64 + cc * 8 + j;
      }
    }
    __syncthreads();  // drains vmcnt (stage done) + fences buffer reuse
  }

  // ---- L1 epilogue -> smRF[128][136] bf16; stage rw2 -> w2l ----
  u16* smRF = (u16*)sm;
  u16* w2l = (u16*)(sm + 34816);
  u16* h2 = (u16*)(sm + 52224);
#pragma unroll
  for (int j = 0; j < 4; ++j) {
    const int col = wn * 64 + j * 16 + fr;
    const float bias = bf2f(rb1[col]);
#pragma unroll
    for (int i = 0; i < 4; ++i) {
      const int rbase = wm * 64 + i * 16 + fq * 4;
#pragma unroll
      for (int r = 0; r < 4; ++r)
        smRF[(rbase + r) * 136 + col] = f2bf(relu(acc[i][j][r] + bias));
    }
  }
  for (int q = t; q < 1024; q += 256) {  // rw2[64][128] -> LDS
    const int rr = q >> 4, cc = q & 15;
    *(s16x8*)(w2l + rr * 136 + cc * 8) = *(const s16x8*)(rw2 + rr * 128 + cc * 8);
  }
  __syncthreads();

  // ---- layer2 MFMA: [128][128] @ rw2^T -> h2[128][72] bf16 ----
  f32x4 c2[4][2];
#pragma unroll
  for (int i = 0; i < 4; ++i)
#pragma unroll
    for (int j = 0; j < 2; ++j) c2[i][j] = f32x4{0.f, 0.f, 0.f, 0.f};
#pragma unroll
  for (int ks = 0; ks < 4; ++ks) {
    s16x8 a2[4], b2[2];
#pragma unroll
    for (int i = 0; i < 4; ++i)
      a2[i] = *(const s16x8*)(smRF + (wm * 64 + i * 16 + fr) * 136 + ks * 32 + fq * 8);
#pragma unroll
    for (int j = 0; j < 2; ++j)
      b2[j] = *(const s16x8*)(w2l + (wn * 32 + j * 16 + fr) * 136 + ks * 32 + fq * 8);
#pragma unroll
    for (int i = 0; i < 4; ++i)
#pragma unroll
      for (int j = 0; j < 2; ++j) c2[i][j] = mfma16(a2[i], b2[j], c2[i][j]);
  }
#pragma unroll
  for (int j = 0; j < 2; ++j) {
    const int col = wn * 32 + j * 16 + fr;
    const float b2v = bf2f(rb2[col]);
#pragma unroll
    for (int i = 0; i < 4; ++i) {
      const int rbase = wm * 64 + i * 16 + fq * 4;
#pragma unroll
      for (int r = 0; r < 4; ++r)
        h2[(rbase + r) * 72 + col] = f2bf(relu(c2[i][j][r] + b2v));
    }
  }
  __syncthreads();

  // ---- layers 3-5: 2 threads per row (hs = output half) ----
  const int r3 = t >> 1, hs = t & 1;
  const u16* h2row = h2 + r3 * 72;
  float h3a[16];
#pragma unroll
  for (int o = 0; o < 16; ++o) h3a[o] = bf2f(rb3[hs * 16 + o]);
#pragma unroll 2
  for (int kc = 0; kc < 8; ++kc) {
    s16x8 hv = *(const s16x8*)(h2row + kc * 8);
    float hf[8];
#pragma unroll
    for (int j = 0; j < 8; ++j) hf[j] = bf2f((u16)hv[j]);
#pragma unroll
    for (int o = 0; o < 16; ++o) {
      s16x8 wv = *(const s16x8*)(rw3 + (size_t)(hs * 16 + o) * 64 + kc * 8);
#pragma unroll
      for (int j = 0; j < 8; ++j) h3a[o] += hf[j] * bf2f((u16)wv[j]);
    }
  }
  // pairwise exchange: vo = own half (logical offset hs*16), vp = partner half
  float vo[16], vp[16];
#pragma unroll
  for (int o = 0; o < 16; ++o) {
    vo[o] = relu(h3a[o]);
    vp[o] = __shfl_xor(vo[o], 1);
  }
  float h4[4];
#pragma unroll
  for (int oo = 0; oo < 4; ++oo) {
    const int o = hs * 4 + oo;
    float s1 = 0.f, s2 = 0.f;
#pragma unroll
    for (int k = 0; k < 16; ++k) {
      s1 += vo[k] * bf2f(rw4[o * 32 + hs * 16 + k]);
      s2 += vp[k] * bf2f(rw4[o * 32 + (1 - hs) * 16 + k]);
    }
    h4[oo] = relu(s1 + s2 + bf2f(rb4[o]));
  }
  float sp = 0.f;
#pragma unroll
  for (int oo = 0; oo < 4; ++oo) sp += h4[oo] * bf2f(rw5[hs * 4 + oo]);
  const float sfull = sp + __shfl_xor(sp, 1) + bf2f(rb5[0]);
  const int tp2 = __shfl_xor(ty, 1);
  const int tmax = ty > tp2 ? ty : tp2;
  if (hs == 0) atomicMax(rgws + tmax, encf(sfull));
}

// ---------------- finale ----------------
template <int F32>
__global__ __launch_bounds__(256) void k_fin(
    const unsigned* __restrict__ egws, const unsigned* __restrict__ rgws,
    const float* __restrict__ tpart, const void* __restrict__ tb1,
    const void* __restrict__ tw2, const void* __restrict__ tb2,
    const void* __restrict__ wih, const void* __restrict__ whh,
    const void* __restrict__ bih, const void* __restrict__ bhh,
    const void* __restrict__ hidden, const void* __restrict__ aw,
    const void* __restrict__ ab, const void* __restrict__ amask,
    void* __restrict__ outp, const unsigned* __restrict__ flag) {
  if (*flag != (unsigned)F32) return;
  __shared__ float env[208];
  __shared__ float th1[64];
  __shared__ float gx[384], gh[384];
  __shared__ float hv[128], hid[128];
  __shared__ float red[256];
  const int t = threadIdx.x;
  if (t < 64) {
    unsigned e = egws[t];
    env[t] = e ? decf(e) : 0.f;
    th1[t] = relu(tpart[t] + ld1<F32>(tb1, t));
  }
  if (t >= 64 && t < 192) {
    unsigned e = rgws[t - 64];
    env[t] = e ? decf(e) : 0.f;
  }
  if (t < 128) hid[t] = ld1<F32>(hidden, t);
  __syncthreads();
  if (t < 16) {
    float a = ld1<F32>(tb2, t);
    for (int k = 0; k < 64; k += 8) {
      float wf[8];
      loadf8<F32>(tw2, t * 64 + k, wf);
#pragma unroll
      for (int j = 0; j < 8; ++j) a += th1[k + j] * wf[j];
    }
    env[192 + t] = a;
  }
  __syncthreads();
  for (int o = t; o < 384; o += 256) {
    float ax = ld1<F32>(bih, o);
#pragma unroll 2
    for (int c = 0; c < 26; ++c) {
      float wf[8];
      loadf8<F32>(wih, (size_t)o * 208 + c * 8, wf);
#pragma unroll
      for (int j = 0; j < 8; ++j) ax += env[c * 8 + j] * wf[j];
    }
    gx[o] = ax;
    float ah = ld1<F32>(bhh, o);
#pragma unroll 2
    for (int c = 0; c < 16; ++c) {
      float wf[8];
      loadf8<F32>(whh, (size_t)o * 128 + c * 8, wf);
#pragma unroll
      for (int j = 0; j < 8; ++j) ah += hid[c * 8 + j] * wf[j];
    }
    gh[o] = ah;
  }
  __syncthreads();
  if (t < 128) {
    float r = 1.f / (1.f + expf(-(gx[t] + gh[t])));
    float z = 1.f / (1.f + expf(-(gx[128 + t] + gh[128 + t])));
    float n = tanhf(gx[256 + t] + r * gh[256 + t]);
    hv[t] = (1.f - z) * n + z * hid[t];
  }
  __syncthreads();
  float s = ld1<F32>(ab, t);
#pragma unroll 4
  for (int c = 0; c < 16; ++c) {
    float wf[8];
    loadf8<F32>(aw, (size_t)t * 128 + c * 8, wf);
#pragma unroll
    for (int j = 0; j < 8; ++j) s += hv[c * 8 + j] * wf[j];
  }
  red[t] = s;
  __syncthreads();
  for (int st = 128; st > 0; st >>= 1) {
    if (t < st) red[t] = fmaxf(red[t], red[t + st]);
    __syncthreads();
  }
  float m = red[0];
  __syncthreads();
  float e = expf(s - m);
  red[t] = e;
  __syncthreads();
  for (int st = 128; st > 0; st >>= 1) {
    if (t < st) red[t] += red[t + st];
    __syncthreads();
  }
  float v = e * (1.f / red[0]) * ld1<F32>(amask, t);
  if (F32) ((float*)outp)[t] = v;
  else ((u16*)outp)[t] = f2bf(v);
}

extern "C" void kernel_launch(void* const* d_in, const int* in_sizes, int n_in,
                              void* d_out, int out_size, void* d_ws, size_t ws_size,
                              hipStream_t stream) {
  const void* entity = d_in[0];
  const void* rel    = d_in[1];
  const void* target = d_in[2];
  const void* amask  = d_in[3];
  const void* ew1 = d_in[4];  const void* eb1 = d_in[5];
  const void* ew2 = d_in[6];  const void* eb2 = d_in[7];
  const void* ew3 = d_in[8];  const void* eb3 = d_in[9];
  const void* rw1 = d_in[10]; const void* rb1 = d_in[11];
  const void* rw2 = d_in[12]; const void* rb2 = d_in[13];
  const void* rw3 = d_in[14]; const void* rb3 = d_in[15];
  const void* rw4 = d_in[16]; const void* rb4 = d_in[17];
  const void* rw5 = d_in[18]; const void* rb5 = d_in[19];
  const void* tw1 = d_in[20]; const void* tb1 = d_in[21];
  const void* tw2 = d_in[22]; const void* tb2 = d_in[23];
  const void* wih = d_in[24]; const void* whh = d_in[25];
  const void* bih = d_in[26]; const void* bhh = d_in[27];
  const void* hidden = d_in[28];
  const void* aw = d_in[29];  const void* ab = d_in[30];

  unsigned* ws = (unsigned*)d_ws;
  unsigned* egws = ws;                // [64]
  unsigned* rgws = ws + 64;           // [128]
  float* tpart = (float*)(ws + 192);  // [64]
  const unsigned* flag = ws + 256;    // [1]: 1 = f32 inputs

  hipLaunchKernelGGL(k_detect, dim3(1), dim3(256), 0, stream,
                     (const u16*)entity, (const u16*)rel, ws);

  hipLaunchKernelGGL((k_ent<0>), dim3(64), dim3(256), 0, stream,
                     entity, ew1, eb1, ew2, eb2, ew3, eb3, egws, flag);
  hipLaunchKernelGGL((k_ent<1>), dim3(64), dim3(256), 0, stream,
                     entity, ew1, eb1, ew2, eb2, ew3, eb3, egws, flag);

  hipLaunchKernelGGL((k_tgt<0>), dim3(256), dim3(256), 0, stream, target, tw1, tpart, flag);
  hipLaunchKernelGGL((k_tgt<1>), dim3(256), dim3(256), 0, stream, target, tw1, tpart, flag);

  hipLaunchKernelGGL(k_relb, dim3(512), dim3(256), 0, stream,
                     (const u16*)rel, (const u16*)rw1, (const u16*)rb1,
                     (const u16*)rw2, (const u16*)rb2, (const u16*)rw3,
                     (const u16*)rb3, (const u16*)rw4, (const u16*)rb4,
                     (const u16*)rw5, (const u16*)rb5, rgws, flag);
  hipLaunchKernelGGL((k_rel<1>), dim3(512), dim3(256), 0, stream,
                     rel, rw1, rb1, rw2, rb2, rw3, rb3, rw4, rb4, rw5, rb5, rgws, flag);

  hipLaunchKernelGGL((k_fin<0>), dim3(1), dim3(256), 0, stream,
                     egws, rgws, tpart, tb1, tw2, tb2, wih, whh, bih, bhh,
                     hidden, aw, ab, amask, d_out, flag);
  hipLaunchKernelGGL((k_fin<1>), dim3(1), dim3(256), 0, stream,
                     egws, rgws, tpart, tb1, tw2, tb2, wih, whh, bih, bhh,
                     hidden, aw, ab, amask, d_out, flag);
}